// Round 8
// baseline (9592.451 us; speedup 1.0000x reference)
//
#include <hip/hip_runtime.h>
#include <stdint.h>

// f32 forward of bin_weight exactly as the reference computes it:
// q = 0.1f*sign(w); return w + (q - w), each op IEEE f32.
__device__ __forceinline__ float dance(float w) {
  float q = w > 0.f ? 0.1f : (w < 0.f ? -0.1f : 0.0f);
  float r = __fsub_rn(q, w);
  return __fadd_rn(w, r);
}

__device__ __forceinline__ int sgn(float u) {
  return u > 0.f ? 1 : (u < 0.f ? -1 : 0);
}

// dance, keeping original [oc][k] layout
__global__ void pack_dance_same(const float* __restrict__ w,
                                float* __restrict__ o, int n) {
  int i = blockIdx.x * 256 + threadIdx.x;
  if (i < n) o[i] = dance(w[i]);
}

// transpose+dance: w[oc][k] -> out[k][oc]
__global__ void pack_dance_T(const float* __restrict__ w, float* __restrict__ out,
                             int OC, int K) {
  int idx = blockIdx.x * 256 + threadIdx.x;
  if (idx >= OC * K) return;
  int oc = idx / K, k = idx - oc * K;
  out[(size_t)k * OC + oc] = dance(w[idx]);
}

// ---------------- conv1: inverted slot loop + sched fences + VGPR cap ----------------
// x(128,1,16000) stride4 VALID -> 3981 pos; +b1; bn; sign; pool4 -> a1[b][995][128] i8
// Chain (b,tp,g,oc): z = seq FMA k=0..79. For slot s ascending, chain (p,g) takes
// q = s-4p-g when 0<=q<20; per chain q ascends with s -> bit-identical order.
// sched_barrier(0) per slot stops cross-iteration ds_read hoisting (r7: 256 VGPR spill).
__global__ __launch_bounds__(128, 4) void conv1_fast(
    const float* __restrict__ x, const float* __restrict__ wd1,
    const float* __restrict__ b1, const float* __restrict__ s1,
    const float* __restrict__ o1, int8_t* __restrict__ a1) {
  __shared__ __align__(16) float xs[144];
  const int tid = threadIdx.x;            // oc
  const int b = blockIdx.y;
  float wreg[80];
  const float* wrow = wd1 + (size_t)tid * 80;
#pragma unroll
  for (int k4 = 0; k4 < 20; ++k4)
    *(float4*)&wreg[k4 * 4] = *(const float4*)(wrow + k4 * 4);
  const float bv = b1[tid], sv = s1[tid], ov = o1[tid];

#pragma unroll 1
  for (int gi = 0; gi < 4; ++gi) {
    const int tpg = blockIdx.x * 4 + gi;  // 249 groups cover tp 0..994
    const int tp0 = tpg * 4;
    if (tp0 >= 995) break;
    const int x0 = 16 * tp0;
    __syncthreads();
    for (int i = tid; i < 140; i += 128)
      xs[i] = x[(size_t)b * 16000 + min(x0 + i, 15999)];
    __syncthreads();

    const float4* x4 = (const float4*)xs;
    float z[16];                          // [p][g]
#pragma unroll
    for (int u = 0; u < 16; ++u) z[u] = 0.f;
    float4 v = x4[0];
#pragma unroll
    for (int s = 0; s < 35; ++s) {        // slots 0..34
      float4 vn = (s < 34) ? x4[s + 1] : make_float4(0.f, 0.f, 0.f, 0.f);
#pragma unroll
      for (int p = 0; p < 4; ++p)
#pragma unroll
        for (int g = 0; g < 4; ++g) {
          const int q = s - 4 * p - g;    // compile-time after unroll
          if (q >= 0 && q < 20) {
            float zz = z[p * 4 + g];
            zz = __builtin_fmaf(wreg[4 * q + 0], v.x, zz);
            zz = __builtin_fmaf(wreg[4 * q + 1], v.y, zz);
            zz = __builtin_fmaf(wreg[4 * q + 2], v.z, zz);
            zz = __builtin_fmaf(wreg[4 * q + 3], v.w, zz);
            z[p * 4 + g] = zz;
          }
        }
      v = vn;
      __builtin_amdgcn_sched_barrier(0);  // fence: no cross-slot motion
    }

#pragma unroll
    for (int p = 0; p < 4; ++p) {
      const int tp = tp0 + p;
      if (tp < 995) {
        int m = -2;
#pragma unroll
        for (int g = 0; g < 4; ++g) {
          float y = __fadd_rn(z[p * 4 + g], bv);
          float t2 = __fmul_rn(y, sv);
          float u = __fadd_rn(t2, ov);
          m = max(m, sgn(u));
        }
        a1[((size_t)b * 995 + tp) * 128 + tid] = (int8_t)m;
      }
    }
  }
}

// ---------------- convN (KW=3): shared LDS window, [oc][k] dword4 weights ----------------
// Chain (b,tp,g,oc): z = seq FMA over k = i*3+h ascending (ii outer, h inner).
template <int CIN, int COUT, int TY, int NTP, int NB, bool OUTF>
__global__ __launch_bounds__(COUT * TY) void convN_fast(
    const int8_t* __restrict__ ain, const float* __restrict__ wd,
    const float* __restrict__ bias, const float* __restrict__ bns,
    const float* __restrict__ bno, void* __restrict__ aout,
    int Tin, int TPout) {
  constexpr int ROWS = 4 * TY * NTP + 2;
  constexpr int NT = COUT * TY;
  __shared__ __align__(16) float as_[NB][ROWS][CIN];
  const int tid = threadIdx.x;
  const int oc = tid % COUT;
  const int ty = tid / COUT;
  const int tp0 = blockIdx.x * (TY * NTP);
  const int b0 = blockIdx.y * NB;
  for (int t = tid; t < NB * ROWS * CIN; t += NT) {
    int nb = t / (ROWS * CIN);
    int rem = t - nb * (ROWS * CIN);
    int r = rem / CIN, c = rem - r * CIN;
    int gr = min(4 * tp0 + r, Tin - 1);
    as_[nb][r][c] = (float)ain[((size_t)(b0 + nb) * Tin + gr) * CIN + c];
  }
  __syncthreads();

  const float* wrow = wd + (size_t)oc * (CIN * 3);
  float z[NB][NTP][4] = {};
  for (int i = 0; i < CIN; i += 4) {
    float wf[12];                          // k = 3i .. 3i+11 (16B aligned)
    *(float4*)(wf + 0) = *(const float4*)(wrow + i * 3);
    *(float4*)(wf + 4) = *(const float4*)(wrow + i * 3 + 4);
    *(float4*)(wf + 8) = *(const float4*)(wrow + i * 3 + 8);
#pragma unroll
    for (int nb = 0; nb < NB; ++nb)
#pragma unroll
      for (int p = 0; p < NTP; ++p) {
        const int rbase = 4 * (NTP * ty + p);
        float r6[6][4];
#pragma unroll
        for (int r = 0; r < 6; ++r)
          *(float4*)r6[r] = *(const float4*)&as_[nb][rbase + r][i];
#pragma unroll
        for (int g = 0; g < 4; ++g) {
          float zz = z[nb][p][g];
#pragma unroll
          for (int ii = 0; ii < 4; ++ii) {
            zz = __builtin_fmaf(wf[ii * 3 + 0], r6[g + 0][ii], zz);
            zz = __builtin_fmaf(wf[ii * 3 + 1], r6[g + 1][ii], zz);
            zz = __builtin_fmaf(wf[ii * 3 + 2], r6[g + 2][ii], zz);
          }
          z[nb][p][g] = zz;
        }
      }
  }
  const float bv = bias[oc], sv = bns[oc], ov = bno[oc];
#pragma unroll
  for (int nb = 0; nb < NB; ++nb)
#pragma unroll
    for (int p = 0; p < NTP; ++p) {
      const int tp = tp0 + NTP * ty + p;
      if (tp < TPout) {
        int m = -2;
#pragma unroll
        for (int g = 0; g < 4; ++g) {
          float y = __fadd_rn(z[nb][p][g], bv);
          float t2 = __fmul_rn(y, sv);
          float u = __fadd_rn(t2, ov);
          m = max(m, sgn(u));
        }
        if (OUTF)  // f32, transposed [b][oc][tp] for emb's flat-k streams
          ((float*)aout)[(size_t)(b0 + nb) * (TPout * COUT) + (size_t)oc * TPout + tp] =
              (float)m;
        else
          ((int8_t*)aout)[((size_t)(b0 + nb) * TPout + tp) * COUT + oc] = (int8_t)m;
      }
    }
}

// ---------------- emb: a4f[b][k] f32 (k=ic*14+h), wdE[oc][k]; flat k streams ----------------
__global__ __launch_bounds__(64) void emb_fast(
    const float* __restrict__ a4f, const float* __restrict__ wdE,
    const float* __restrict__ bemb, float* __restrict__ yemb) {
  const int oc = blockIdx.x * 64 + threadIdx.x;
  const int b0 = blockIdx.y * 2;
  const float* wrow = wdE + (size_t)oc * 7168;
  const float* pa = a4f + (size_t)b0 * 7168;
  const float* pb = pa + 7168;
  float za = 0.f, zb = 0.f;
  for (int k = 0; k < 7168; k += 4) {
    const float4 w4 = *(const float4*)(wrow + k);
    const float4 av = *(const float4*)(pa + k);
    const float4 bv = *(const float4*)(pb + k);
    za = __builtin_fmaf(w4.x, av.x, za); zb = __builtin_fmaf(w4.x, bv.x, zb);
    za = __builtin_fmaf(w4.y, av.y, za); zb = __builtin_fmaf(w4.y, bv.y, zb);
    za = __builtin_fmaf(w4.z, av.z, za); zb = __builtin_fmaf(w4.z, bv.z, zb);
    za = __builtin_fmaf(w4.w, av.w, za); zb = __builtin_fmaf(w4.w, bv.w, zb);
  }
  const float be = bemb[oc];
  yemb[(size_t)b0 * 512 + oc] = __fadd_rn(za, be);
  yemb[(size_t)(b0 + 1) * 512 + oc] = __fadd_rn(zb, be);
}

// ---------------- fc1 + bn + sign + fc2 ----------------
__global__ __launch_bounds__(256) void fc_np(
    const float* __restrict__ yemb, const float* __restrict__ w1t,
    const float* __restrict__ s1, const float* __restrict__ o1,
    const float* __restrict__ w2t, float* __restrict__ out) {
  __shared__ float ys[512];
  __shared__ float a5[256];
  const int b = blockIdx.x;
  const int tid = threadIdx.x;
  for (int i = tid; i < 512; i += 256) ys[i] = yemb[(size_t)b * 512 + i];
  __syncthreads();
  float z = 0.f;
  for (int k = 0; k < 512; ++k)
    z = __builtin_fmaf(w1t[k * 256 + tid], ys[k], z);
  float t = __fmul_rn(z, s1[tid]);
  float u = __fadd_rn(t, o1[tid]);
  a5[tid] = u > 0.f ? 1.f : (u < 0.f ? -1.f : 0.f);
  __syncthreads();
  if (tid < 35) {
    float z2 = 0.f;
    for (int k = 0; k < 256; ++k)
      z2 = __builtin_fmaf(w2t[k * 35 + tid], a5[k], z2);
    out[(size_t)b * 35 + tid] = z2;
  }
}

extern "C" void kernel_launch(void* const* d_in, const int* in_sizes, int n_in,
                              void* d_out, int out_size, void* d_ws, size_t ws_size,
                              hipStream_t stream) {
  const float* x    = (const float*)d_in[0];
  const float* w1   = (const float*)d_in[1];
  const float* b1   = (const float*)d_in[2];
  const float* bn1s = (const float*)d_in[3];
  const float* bn1b = (const float*)d_in[4];
  const float* w2   = (const float*)d_in[5];
  const float* b2   = (const float*)d_in[6];
  const float* bn2s = (const float*)d_in[7];
  const float* bn2b = (const float*)d_in[8];
  const float* w3   = (const float*)d_in[9];
  const float* b3   = (const float*)d_in[10];
  const float* bn3s = (const float*)d_in[11];
  const float* bn3b = (const float*)d_in[12];
  const float* w5   = (const float*)d_in[13];
  const float* b5   = (const float*)d_in[14];
  const float* bn5s = (const float*)d_in[15];
  const float* bn5b = (const float*)d_in[16];
  const float* wemb = (const float*)d_in[17];
  const float* bemb = (const float*)d_in[18];
  const float* wfc1 = (const float*)d_in[19];
  const float* fc1s = (const float*)d_in[20];
  const float* fc1b = (const float*)d_in[21];
  const float* wfc2 = (const float*)d_in[22];
  float* out = (float*)d_out;

  uint8_t* ws = (uint8_t*)d_ws;
  size_t off = 0;
  auto carve = [&](size_t bytes) {
    void* p = ws + off;
    off = (off + bytes + 255) & ~(size_t)255;
    return p;
  };
  int8_t* a1   = (int8_t*)carve((size_t)128 * 995 * 128);
  int8_t* a2   = (int8_t*)carve((size_t)128 * 248 * 128);
  int8_t* a3   = (int8_t*)carve((size_t)128 * 61 * 256);
  float* a4f   = (float*)carve((size_t)128 * 512 * 14 * 4);   // [b][oc][tp]
  float* yemb  = (float*)carve((size_t)128 * 512 * 4);
  float* wd1   = (float*)carve((size_t)128 * 80 * 4);         // [oc][k]
  float* wd2   = (float*)carve((size_t)128 * 384 * 4);        // [oc][k]
  float* wd3   = (float*)carve((size_t)256 * 384 * 4);
  float* wd5   = (float*)carve((size_t)512 * 768 * 4);
  float* wdE   = (float*)carve((size_t)512 * 7168 * 4);
  float* fc1t  = (float*)carve((size_t)512 * 256 * 4);        // [k][oc]
  float* fc2t  = (float*)carve((size_t)256 * 35 * 4);

  pack_dance_same<<<dim3((128 * 80 + 255) / 256), 256, 0, stream>>>(w1, wd1, 128 * 80);
  pack_dance_same<<<dim3((128 * 384 + 255) / 256), 256, 0, stream>>>(w2, wd2, 128 * 384);
  pack_dance_same<<<dim3((256 * 384 + 255) / 256), 256, 0, stream>>>(w3, wd3, 256 * 384);
  pack_dance_same<<<dim3((512 * 768 + 255) / 256), 256, 0, stream>>>(w5, wd5, 512 * 768);
  pack_dance_same<<<dim3((512 * 7168 + 255) / 256), 256, 0, stream>>>(wemb, wdE, 512 * 7168);
  pack_dance_T<<<dim3((256 * 512 + 255) / 256), 256, 0, stream>>>(wfc1, fc1t, 256, 512);
  pack_dance_T<<<dim3((35 * 256 + 255) / 256), 256, 0, stream>>>(wfc2, fc2t, 35, 256);

  // conv1: 63 blocks x 4 groups of 4 pooled positions; 128 batches
  conv1_fast<<<dim3(63, 128), 128, 0, stream>>>(x, wd1, b1, bn1s, bn1b, a1);

  // conv2: Tin=995 TPout=248; 128oc x TY2 x NTP2 x NB2 -> grid(62,64), 256 thr
  convN_fast<128, 128, 2, 2, 2, false><<<dim3(62, 64), 256, 0, stream>>>(
      a1, wd2, b2, bn2s, bn2b, a2, 995, 248);
  // conv3: Tin=248 TPout=61; 256oc x TY1 x NTP2 x NB2 -> grid(31,64), 256 thr
  convN_fast<128, 256, 1, 2, 2, false><<<dim3(31, 64), 256, 0, stream>>>(
      a2, wd3, b3, bn3s, bn3b, a3, 248, 61);
  // conv5: Tin=61 TPout=14; 512oc x TY1 x NTP1 x NB2 -> grid(14,64), 512 thr, f32-T out
  convN_fast<256, 512, 1, 1, 2, true><<<dim3(14, 64), 512, 0, stream>>>(
      a3, wd5, b5, bn5s, bn5b, a4f, 61, 14);

  emb_fast<<<dim3(8, 64), 64, 0, stream>>>(a4f, wdE, bemb, yemb);

  fc_np<<<dim3(128), 256, 0, stream>>>(yemb, fc1t, fc1s, fc1b, fc2t, out);
}

// Round 9
// 1005.655 us; speedup vs baseline: 9.5385x; 9.5385x over previous
//
#include <hip/hip_runtime.h>
#include <stdint.h>

// f32 forward of bin_weight exactly as the reference computes it:
// q = 0.1f*sign(w); return w + (q - w), each op IEEE f32.
__device__ __forceinline__ float dance(float w) {
  float q = w > 0.f ? 0.1f : (w < 0.f ? -0.1f : 0.0f);
  float r = __fsub_rn(q, w);
  return __fadd_rn(w, r);
}

__device__ __forceinline__ int sgn(float u) {
  return u > 0.f ? 1 : (u < 0.f ? -1 : 0);
}

// dance, keeping original [oc][k] layout
__global__ void pack_dance_same(const float* __restrict__ w,
                                float* __restrict__ o, int n) {
  int i = blockIdx.x * 256 + threadIdx.x;
  if (i < n) o[i] = dance(w[i]);
}

// transpose+dance: w[oc][k] -> out[k][oc]
__global__ void pack_dance_T(const float* __restrict__ w, float* __restrict__ out,
                             int OC, int K) {
  int idx = blockIdx.x * 256 + threadIdx.x;
  if (idx >= OC * K) return;
  int oc = idx / K, k = idx - oc * K;
  out[(size_t)k * OC + oc] = dance(w[idx]);
}

// ---------------- conv1 (round-5 known-good formulation, verbatim) ----------------
// x(128,1,16000) stride4 VALID -> 3981 pos; +b1; bn; sign; pool4 -> a1[b][995][128] i8
// Chain (b,tp,g,oc): z = seq FMA k=0..79, bit-identical to the round-4 PASS order.
// Direct per-use LDS float4 reads; wreg[80]; no launch-bounds caps, no sched fences.
__global__ __launch_bounds__(128) void conv1_fast(
    const float* __restrict__ x, const float* __restrict__ w1t,
    const float* __restrict__ b1, const float* __restrict__ s1,
    const float* __restrict__ o1, int8_t* __restrict__ a1) {
  __shared__ float xs[2][112];               // per-b window: 2*16+76 = 108 floats
  const int tid = threadIdx.x;               // oc
  const int tp0 = blockIdx.x * 2;            // 498 groups (995 -> clamp tail)
  const int b0 = blockIdx.y * 2;
  for (int t = tid; t < 2 * 108; t += 128) {
    int nb = t / 108, j = t - nb * 108;
    xs[nb][j] = x[(size_t)(b0 + nb) * 16000 + min(16 * tp0 + j, 15999)];
  }
  // one-time coalesced weight preload -> 80 registers (constant-indexed)
  float wreg[80];
#pragma unroll
  for (int k = 0; k < 80; ++k) wreg[k] = w1t[k * 128 + tid];
  __syncthreads();

  const int sb0 = 4 * (min(tp0 + 0, 994) - tp0);   // float4-slot base per p (0 / 4)
  const int sb1 = 4 * (min(tp0 + 1, 994) - tp0);
  float z[2][2][4] = {};                     // [nb][p][g]
  const float4* x40 = (const float4*)xs[0];
  const float4* x41 = (const float4*)xs[1];
#pragma unroll
  for (int q = 0; q < 20; ++q) {             // k = 4q + ii
#pragma unroll
    for (int nb = 0; nb < 2; ++nb) {
      const float4* x4 = nb ? x41 : x40;
#pragma unroll
      for (int p = 0; p < 2; ++p) {
        const int sb = p ? sb1 : sb0;
        float4 v0 = x4[sb + q + 0];
        float4 v1 = x4[sb + q + 1];
        float4 v2 = x4[sb + q + 2];
        float4 v3 = x4[sb + q + 3];
        float4 vv[4] = {v0, v1, v2, v3};
#pragma unroll
        for (int g = 0; g < 4; ++g) {
          float zz = z[nb][p][g];
          zz = __builtin_fmaf(wreg[4 * q + 0], vv[g].x, zz);
          zz = __builtin_fmaf(wreg[4 * q + 1], vv[g].y, zz);
          zz = __builtin_fmaf(wreg[4 * q + 2], vv[g].z, zz);
          zz = __builtin_fmaf(wreg[4 * q + 3], vv[g].w, zz);
          z[nb][p][g] = zz;
        }
      }
    }
  }
  const float bv = b1[tid], sv = s1[tid], ov = o1[tid];
#pragma unroll
  for (int nb = 0; nb < 2; ++nb)
#pragma unroll
    for (int p = 0; p < 2; ++p) {
      int m = -2;
#pragma unroll
      for (int g = 0; g < 4; ++g) {
        float y = __fadd_rn(z[nb][p][g], bv);
        float t2 = __fmul_rn(y, sv);
        float u = __fadd_rn(t2, ov);
        m = max(m, sgn(u));
      }
      int tpc = min(tp0 + p, 994);
      a1[((size_t)(b0 + nb) * 995 + tpc) * 128 + tid] = (int8_t)m;
    }
}

// ---------------- convN (KW=3): shared LDS window, [oc][k] dword4 weights ----------------
// Chain (b,tp,g,oc): z = seq FMA over k = i*3+h ascending (ii outer, h inner).
template <int CIN, int COUT, int TY, int NTP, int NB, bool OUTF>
__global__ __launch_bounds__(COUT * TY) void convN_fast(
    const int8_t* __restrict__ ain, const float* __restrict__ wd,
    const float* __restrict__ bias, const float* __restrict__ bns,
    const float* __restrict__ bno, void* __restrict__ aout,
    int Tin, int TPout) {
  constexpr int ROWS = 4 * TY * NTP + 2;
  constexpr int NT = COUT * TY;
  __shared__ __align__(16) float as_[NB][ROWS][CIN];
  const int tid = threadIdx.x;
  const int oc = tid % COUT;
  const int ty = tid / COUT;
  const int tp0 = blockIdx.x * (TY * NTP);
  const int b0 = blockIdx.y * NB;
  for (int t = tid; t < NB * ROWS * CIN; t += NT) {
    int nb = t / (ROWS * CIN);
    int rem = t - nb * (ROWS * CIN);
    int r = rem / CIN, c = rem - r * CIN;
    int gr = min(4 * tp0 + r, Tin - 1);
    as_[nb][r][c] = (float)ain[((size_t)(b0 + nb) * Tin + gr) * CIN + c];
  }
  __syncthreads();

  const float* wrow = wd + (size_t)oc * (CIN * 3);
  float z[NB][NTP][4] = {};
  for (int i = 0; i < CIN; i += 4) {
    float wf[12];                          // k = 3i .. 3i+11 (16B aligned)
    *(float4*)(wf + 0) = *(const float4*)(wrow + i * 3);
    *(float4*)(wf + 4) = *(const float4*)(wrow + i * 3 + 4);
    *(float4*)(wf + 8) = *(const float4*)(wrow + i * 3 + 8);
#pragma unroll
    for (int nb = 0; nb < NB; ++nb)
#pragma unroll
      for (int p = 0; p < NTP; ++p) {
        const int rbase = 4 * (NTP * ty + p);
        float r6[6][4];
#pragma unroll
        for (int r = 0; r < 6; ++r)
          *(float4*)r6[r] = *(const float4*)&as_[nb][rbase + r][i];
#pragma unroll
        for (int g = 0; g < 4; ++g) {
          float zz = z[nb][p][g];
#pragma unroll
          for (int ii = 0; ii < 4; ++ii) {
            zz = __builtin_fmaf(wf[ii * 3 + 0], r6[g + 0][ii], zz);
            zz = __builtin_fmaf(wf[ii * 3 + 1], r6[g + 1][ii], zz);
            zz = __builtin_fmaf(wf[ii * 3 + 2], r6[g + 2][ii], zz);
          }
          z[nb][p][g] = zz;
        }
      }
  }
  const float bv = bias[oc], sv = bns[oc], ov = bno[oc];
#pragma unroll
  for (int nb = 0; nb < NB; ++nb)
#pragma unroll
    for (int p = 0; p < NTP; ++p) {
      const int tp = tp0 + NTP * ty + p;
      if (tp < TPout) {
        int m = -2;
#pragma unroll
        for (int g = 0; g < 4; ++g) {
          float y = __fadd_rn(z[nb][p][g], bv);
          float t2 = __fmul_rn(y, sv);
          float u = __fadd_rn(t2, ov);
          m = max(m, sgn(u));
        }
        if (OUTF)  // f32, transposed [b][oc][tp] for emb's flat-k streams
          ((float*)aout)[(size_t)(b0 + nb) * (TPout * COUT) + (size_t)oc * TPout + tp] =
              (float)m;
        else
          ((int8_t*)aout)[((size_t)(b0 + nb) * TPout + tp) * COUT + oc] = (int8_t)m;
      }
    }
}

// ---------------- emb: coalesced [k][oc] weights (round-4-PASS chain order) ----------------
// a4f[b][k] f32 (k=ic*14+h); wEt[k][oc]; chain: i outer, h inner, single accumulator.
__global__ __launch_bounds__(256) void emb_coal(
    const float* __restrict__ a4f, const float* __restrict__ wEt,
    const float* __restrict__ bemb, float* __restrict__ yemb) {
  const int oc = blockIdx.x * 256 + threadIdx.x;   // 0..511
  const int b = blockIdx.y;                        // 0..127
  const float* arow = a4f + (size_t)b * 7168;
  float z = 0.f;
  for (int i = 0; i < 512; ++i) {
#pragma unroll
    for (int h = 0; h < 14; ++h) {
      const int k = i * 14 + h;
      float a = arow[k];                           // uniform across block
      float w = wEt[(size_t)k * 512 + oc];         // coalesced across lanes
      z = __builtin_fmaf(w, a, z);
    }
  }
  yemb[(size_t)b * 512 + oc] = __fadd_rn(z, bemb[oc]);
}

// ---------------- fc1 + bn + sign + fc2 ----------------
__global__ __launch_bounds__(256) void fc_np(
    const float* __restrict__ yemb, const float* __restrict__ w1t,
    const float* __restrict__ s1, const float* __restrict__ o1,
    const float* __restrict__ w2t, float* __restrict__ out) {
  __shared__ float ys[512];
  __shared__ float a5[256];
  const int b = blockIdx.x;
  const int tid = threadIdx.x;
  for (int i = tid; i < 512; i += 256) ys[i] = yemb[(size_t)b * 512 + i];
  __syncthreads();
  float z = 0.f;
  for (int k = 0; k < 512; ++k)
    z = __builtin_fmaf(w1t[k * 256 + tid], ys[k], z);
  float t = __fmul_rn(z, s1[tid]);
  float u = __fadd_rn(t, o1[tid]);
  a5[tid] = u > 0.f ? 1.f : (u < 0.f ? -1.f : 0.f);
  __syncthreads();
  if (tid < 35) {
    float z2 = 0.f;
    for (int k = 0; k < 256; ++k)
      z2 = __builtin_fmaf(w2t[k * 35 + tid], a5[k], z2);
    out[(size_t)b * 35 + tid] = z2;
  }
}

extern "C" void kernel_launch(void* const* d_in, const int* in_sizes, int n_in,
                              void* d_out, int out_size, void* d_ws, size_t ws_size,
                              hipStream_t stream) {
  const float* x    = (const float*)d_in[0];
  const float* w1   = (const float*)d_in[1];
  const float* b1   = (const float*)d_in[2];
  const float* bn1s = (const float*)d_in[3];
  const float* bn1b = (const float*)d_in[4];
  const float* w2   = (const float*)d_in[5];
  const float* b2   = (const float*)d_in[6];
  const float* bn2s = (const float*)d_in[7];
  const float* bn2b = (const float*)d_in[8];
  const float* w3   = (const float*)d_in[9];
  const float* b3   = (const float*)d_in[10];
  const float* bn3s = (const float*)d_in[11];
  const float* bn3b = (const float*)d_in[12];
  const float* w5   = (const float*)d_in[13];
  const float* b5   = (const float*)d_in[14];
  const float* bn5s = (const float*)d_in[15];
  const float* bn5b = (const float*)d_in[16];
  const float* wemb = (const float*)d_in[17];
  const float* bemb = (const float*)d_in[18];
  const float* wfc1 = (const float*)d_in[19];
  const float* fc1s = (const float*)d_in[20];
  const float* fc1b = (const float*)d_in[21];
  const float* wfc2 = (const float*)d_in[22];
  float* out = (float*)d_out;

  uint8_t* ws = (uint8_t*)d_ws;
  size_t off = 0;
  auto carve = [&](size_t bytes) {
    void* p = ws + off;
    off = (off + bytes + 255) & ~(size_t)255;
    return p;
  };
  int8_t* a1   = (int8_t*)carve((size_t)128 * 995 * 128);
  int8_t* a2   = (int8_t*)carve((size_t)128 * 248 * 128);
  int8_t* a3   = (int8_t*)carve((size_t)128 * 61 * 256);
  float* a4f   = (float*)carve((size_t)128 * 512 * 14 * 4);   // [b][oc][tp]
  float* yemb  = (float*)carve((size_t)128 * 512 * 4);
  float* w1t   = (float*)carve((size_t)80 * 128 * 4);         // [k][oc]
  float* wd2   = (float*)carve((size_t)128 * 384 * 4);        // [oc][k]
  float* wd3   = (float*)carve((size_t)256 * 384 * 4);
  float* wd5   = (float*)carve((size_t)512 * 768 * 4);
  float* wEt   = (float*)carve((size_t)7168 * 512 * 4);       // [k][oc]
  float* fc1t  = (float*)carve((size_t)512 * 256 * 4);        // [k][oc]
  float* fc2t  = (float*)carve((size_t)256 * 35 * 4);

  pack_dance_T<<<dim3((128 * 80 + 255) / 256), 256, 0, stream>>>(w1, w1t, 128, 80);
  pack_dance_same<<<dim3((128 * 384 + 255) / 256), 256, 0, stream>>>(w2, wd2, 128 * 384);
  pack_dance_same<<<dim3((256 * 384 + 255) / 256), 256, 0, stream>>>(w3, wd3, 256 * 384);
  pack_dance_same<<<dim3((512 * 768 + 255) / 256), 256, 0, stream>>>(w5, wd5, 512 * 768);
  pack_dance_T<<<dim3((512 * 7168 + 255) / 256), 256, 0, stream>>>(wemb, wEt, 512, 7168);
  pack_dance_T<<<dim3((256 * 512 + 255) / 256), 256, 0, stream>>>(wfc1, fc1t, 256, 512);
  pack_dance_T<<<dim3((35 * 256 + 255) / 256), 256, 0, stream>>>(wfc2, fc2t, 35, 256);

  // conv1: 498 tp-pairs x 64 batch-pairs (round-5 geometry)
  conv1_fast<<<dim3(498, 64), 128, 0, stream>>>(x, w1t, b1, bn1s, bn1b, a1);

  // conv2: Tin=995 TPout=248; 128oc x TY2 x NTP2 x NB2 -> grid(62,64), 256 thr
  convN_fast<128, 128, 2, 2, 2, false><<<dim3(62, 64), 256, 0, stream>>>(
      a1, wd2, b2, bn2s, bn2b, a2, 995, 248);
  // conv3: Tin=248 TPout=61; 256oc x TY1 x NTP2 x NB2 -> grid(31,64), 256 thr
  convN_fast<128, 256, 1, 2, 2, false><<<dim3(31, 64), 256, 0, stream>>>(
      a2, wd3, b3, bn3s, bn3b, a3, 248, 61);
  // conv5: Tin=61 TPout=14; 512oc x TY1 x NTP1 x NB2 -> grid(14,64), 512 thr, f32-T out
  convN_fast<256, 512, 1, 1, 2, true><<<dim3(14, 64), 512, 0, stream>>>(
      a3, wd5, b5, bn5s, bn5b, a4f, 61, 14);

  // emb: grid(2,128) x 256 thr -> 1024 waves, coalesced weights
  emb_coal<<<dim3(2, 128), 256, 0, stream>>>(a4f, wEt, bemb, yemb);

  fc_np<<<dim3(128), 256, 0, stream>>>(yemb, fc1t, fc1s, fc1b, fc2t, out);
}